// Round 1
// 121.062 us; speedup vs baseline: 1.1101x; 1.1101x over previous
//
#include <hip/hip_runtime.h>

#define B  4
#define TE 512
#define TD 256
#define DE 512
#define U  128

// ---------------------------------------------------------------------------
// Fused projections, output in EXP DOMAIN: E = exp(2 * (x@W + b)).
// score kernel uses tanh(a+d) = 1 - 2/(Ea*Ed + 1); the constant term of the
// score is e-independent and cancels in softmax.
// blocks 0..255: enc side, output TRANSPOSED as encT[b][u][e] (LDS transpose).
// blocks 256..383: dec side, natural [t][u] layout.
// 8 rows/block, 128 threads, 2 rows/thread (halves W load instructions vs
// 1 row/thread: each W float4 feeds 8 FMAs instead of 4).
// ---------------------------------------------------------------------------
__global__ __launch_bounds__(128) void proj_fused_kernel(
        const float* __restrict__ enc, const float* __restrict__ dec,
        const float* __restrict__ W1w, const float* __restrict__ W1b,
        const float* __restrict__ W2w, const float* __restrict__ W2b,
        float* __restrict__ encT, float* __restrict__ decp){
    __shared__ float4 Xs[8 * 128];              // 8 rows x 512 f32 = 16 KB
    float* T = (float*)Xs;                      // aliased transpose buffer
    const int tid = threadIdx.x;

    const bool is_enc = blockIdx.x < 256;
    const float *X, *W, *bias; int r0;
    if (is_enc){ r0 = blockIdx.x * 8;         X = enc; W = W1w; bias = W1b; }
    else       { r0 = (blockIdx.x - 256) * 8; X = dec; W = W2w; bias = W2b; }

    // stage 8 rows of X (1024 float4), coalesced, 8 per thread
    const float4* Xg = (const float4*)(X + (size_t)r0 * 512);
    #pragma unroll
    for (int j = 0; j < 8; ++j)
        Xs[j * 128 + tid] = Xg[j * 128 + tid];
    __syncthreads();

    const int q = tid & 31;          // u-quad index: u0 = 4q
    const int g = tid >> 5;          // 0..3 -> rows g and g+4
    const float4* W4 = (const float4*)W;   // row d = 32 float4

    float4 acc0 = ((const float4*)bias)[q];
    float4 acc1 = acc0;

    #pragma unroll 2
    for (int d0 = 0; d0 < 512; d0 += 4){
        float4 x0 = Xs[g * 128 + (d0 >> 2)];          // LDS broadcast
        float4 x1 = Xs[(g + 4) * 128 + (d0 >> 2)];
        float4 w0 = W4[(d0 + 0) * 32 + q];
        float4 w1 = W4[(d0 + 1) * 32 + q];
        float4 w2 = W4[(d0 + 2) * 32 + q];
        float4 w3 = W4[(d0 + 3) * 32 + q];
        acc0.x += x0.x*w0.x + x0.y*w1.x + x0.z*w2.x + x0.w*w3.x;
        acc0.y += x0.x*w0.y + x0.y*w1.y + x0.z*w2.y + x0.w*w3.y;
        acc0.z += x0.x*w0.z + x0.y*w1.z + x0.z*w2.z + x0.w*w3.z;
        acc0.w += x0.x*w0.w + x0.y*w1.w + x0.z*w2.w + x0.w*w3.w;
        acc1.x += x1.x*w0.x + x1.y*w1.x + x1.z*w2.x + x1.w*w3.x;
        acc1.y += x1.x*w0.y + x1.y*w1.y + x1.z*w2.y + x1.w*w3.y;
        acc1.z += x1.x*w0.z + x1.y*w1.z + x1.z*w2.z + x1.w*w3.z;
        acc1.w += x1.x*w0.w + x1.y*w1.w + x1.z*w2.w + x1.w*w3.w;
    }

    // exp-domain transform: E = exp(2*p) = exp2(p * 2*log2(e))
    const float C2 = 2.8853900817779268f;
    acc0.x = __builtin_amdgcn_exp2f(acc0.x * C2);
    acc0.y = __builtin_amdgcn_exp2f(acc0.y * C2);
    acc0.z = __builtin_amdgcn_exp2f(acc0.z * C2);
    acc0.w = __builtin_amdgcn_exp2f(acc0.w * C2);
    acc1.x = __builtin_amdgcn_exp2f(acc1.x * C2);
    acc1.y = __builtin_amdgcn_exp2f(acc1.y * C2);
    acc1.z = __builtin_amdgcn_exp2f(acc1.z * C2);
    acc1.w = __builtin_amdgcn_exp2f(acc1.w * C2);

    if (is_enc){
        __syncthreads();                           // Xs reads complete
        // T[u][e_local], u-stride 9 (pad breaks power-of-2 banks)
        T[(4*q + 0)*9 + g]     = acc0.x;
        T[(4*q + 1)*9 + g]     = acc0.y;
        T[(4*q + 2)*9 + g]     = acc0.z;
        T[(4*q + 3)*9 + g]     = acc0.w;
        T[(4*q + 0)*9 + g + 4] = acc1.x;
        T[(4*q + 1)*9 + g + 4] = acc1.y;
        T[(4*q + 2)*9 + g + 4] = acc1.z;
        T[(4*q + 3)*9 + g + 4] = acc1.w;
        __syncthreads();
        const int u  = tid;            // 0..127
        const int b  = r0 >> 9;        // 512 rows per batch
        const int et = r0 & 511;       // e-tile base
        float4 lo = make_float4(T[u*9+0], T[u*9+1], T[u*9+2], T[u*9+3]);
        float4 hi = make_float4(T[u*9+4], T[u*9+5], T[u*9+6], T[u*9+7]);
        float4* row = (float4*)encT + (size_t)(b*U + u)*128 + (et >> 2);
        row[0] = lo; row[1] = hi;
    } else {
        ((float4*)decp)[(size_t)(r0 + g)     * 32 + q] = acc0;   // coalesced
        ((float4*)decp)[(size_t)(r0 + g + 4) * 32 + q] = acc1;
    }
}

// ---------------------------------------------------------------------------
// Score + softmax, exp-factorized tanh:
//   logits[e] = sum_u (-2*V_u) * rcp(Ea[u][e]*Ed[t][u] + 1)
// (differs from the true score by the e-independent constant sum(V)+V_b,
//  which cancels in softmax). 2 VALU + 1 trans per tanh vs 5 VALU + 2 trans.
// block = (b, t-quad), 256 threads: th = tid>>7 handles t0+th and t0+2+th,
// so each Ea quad is loaded ONCE for two t's (halves L1 load instructions).
// ---------------------------------------------------------------------------
__global__ __launch_bounds__(256) void score_kernel(
        const float* __restrict__ encT, const float* __restrict__ decp,
        const float* __restrict__ Vw, float* __restrict__ attn_out){
    __shared__ float4 dp4[128];      // Ed rows t0..t0+3 (4 x 128 f32)
    __shared__ float4 vv4[32];       // -2*V (128 f32)
    __shared__ float redma[4], redmb[4], redsa[4], redsb[4];
    const float* dpf = (const float*)dp4;
    const float* vvf = (const float*)vv4;
    const int tid = threadIdx.x;
    const int b  = blockIdx.x >> 6;
    const int t0 = (blockIdx.x & 63) * 4;

    if (tid < 128){
        dp4[tid] = ((const float4*)decp)[(size_t)(b*TD + t0 + (tid>>5))*32 + (tid&31)];
    } else if (tid < 160){
        float4 v = ((const float4*)Vw)[tid - 128];
        vv4[tid - 128] = make_float4(-2.f*v.x, -2.f*v.y, -2.f*v.z, -2.f*v.w);
    }
    __syncthreads();

    const int th = tid >> 7;         // 0 or 1
    const int eq = tid & 127;        // e-quad: e0 = 4*eq
    const float4* E = (const float4*)encT + (size_t)b*U*128 + eq;
    const float* dA = dpf + th * 128;        // row t0+th
    const float* dB = dpf + (2 + th) * 128;  // row t0+2+th

    float4 sa = make_float4(0.f, 0.f, 0.f, 0.f);
    float4 sb = make_float4(0.f, 0.f, 0.f, 0.f);
    #pragma unroll 4
    for (int u = 0; u < U; ++u){
        float4 A = E[(size_t)u * 128];        // coalesced across e-lanes
        float da = dA[u];
        float db = dB[u];
        float wv = vvf[u];
        sa.x += wv * __builtin_amdgcn_rcpf(fmaf(A.x, da, 1.0f));
        sa.y += wv * __builtin_amdgcn_rcpf(fmaf(A.y, da, 1.0f));
        sa.z += wv * __builtin_amdgcn_rcpf(fmaf(A.z, da, 1.0f));
        sa.w += wv * __builtin_amdgcn_rcpf(fmaf(A.w, da, 1.0f));
        sb.x += wv * __builtin_amdgcn_rcpf(fmaf(A.x, db, 1.0f));
        sb.y += wv * __builtin_amdgcn_rcpf(fmaf(A.y, db, 1.0f));
        sb.z += wv * __builtin_amdgcn_rcpf(fmaf(A.z, db, 1.0f));
        sb.w += wv * __builtin_amdgcn_rcpf(fmaf(A.w, db, 1.0f));
    }

    // two softmaxes per th-group (each t spans 2 waves)
    float ma = fmaxf(fmaxf(sa.x, sa.y), fmaxf(sa.z, sa.w));
    float mb = fmaxf(fmaxf(sb.x, sb.y), fmaxf(sb.z, sb.w));
    for (int o = 32; o > 0; o >>= 1){
        ma = fmaxf(ma, __shfl_xor(ma, o));
        mb = fmaxf(mb, __shfl_xor(mb, o));
    }
    const int w = tid >> 6;
    if ((tid & 63) == 0){ redma[w] = ma; redmb[w] = mb; }
    __syncthreads();
    ma = fmaxf(redma[2*th], redma[2*th + 1]);
    mb = fmaxf(redmb[2*th], redmb[2*th + 1]);

    const float L2E = 1.4426950408889634f;
    float4 pa, pb;
    pa.x = __builtin_amdgcn_exp2f((sa.x - ma) * L2E);
    pa.y = __builtin_amdgcn_exp2f((sa.y - ma) * L2E);
    pa.z = __builtin_amdgcn_exp2f((sa.z - ma) * L2E);
    pa.w = __builtin_amdgcn_exp2f((sa.w - ma) * L2E);
    pb.x = __builtin_amdgcn_exp2f((sb.x - mb) * L2E);
    pb.y = __builtin_amdgcn_exp2f((sb.y - mb) * L2E);
    pb.z = __builtin_amdgcn_exp2f((sb.z - mb) * L2E);
    pb.w = __builtin_amdgcn_exp2f((sb.w - mb) * L2E);
    float sla = (pa.x + pa.y) + (pa.z + pa.w);
    float slb = (pb.x + pb.y) + (pb.z + pb.w);
    for (int o = 32; o > 0; o >>= 1){
        sla += __shfl_xor(sla, o);
        slb += __shfl_xor(slb, o);
    }
    if ((tid & 63) == 0){ redsa[w] = sla; redsb[w] = slb; }
    __syncthreads();
    float inva = __builtin_amdgcn_rcpf(redsa[2*th] + redsa[2*th + 1]);
    float invb = __builtin_amdgcn_rcpf(redsb[2*th] + redsb[2*th + 1]);

    float4* O = (float4*)attn_out;
    O[(size_t)(b*TD + t0 + th)*128 + eq] =
        make_float4(pa.x*inva, pa.y*inva, pa.z*inva, pa.w*inva);
    O[(size_t)(b*TD + t0 + 2 + th)*128 + eq] =
        make_float4(pb.x*invb, pb.y*invb, pb.z*invb, pb.w*invb);
}

// ---------------------------------------------------------------------------
// context[b,t,d] = sum_e attn[b,t,e]*enc[b,e,d].
// block = (b, t-oct, d-half), 512 threads: dq = tid&63 (d-quad within half),
// eq = tid>>6 (e-eighth, 64 e's each). LDS tree-reduce over the 8 e-groups.
// ---------------------------------------------------------------------------
__global__ __launch_bounds__(512) void context_kernel(
        const float* __restrict__ enc, const float* __restrict__ attn,
        float* __restrict__ ctx_out){
    __shared__ float4 at4[8 * 128];      // attn rows [t][e-quad], 16 KB
    __shared__ float4 red4[8 * 256];     // reduce buffer [t][4 groups][64], 32 KB
    const int tid = threadIdx.x;
    const int dh = blockIdx.x & 1;             // d-half
    const int b  = (blockIdx.x >> 1) & 3;      // ~XCD-resident batch
    const int t0 = (blockIdx.x >> 3) * 8;      // t-oct
    const int dq = tid & 63;
    const int eq = tid >> 6;

    // stage 8 attn rows (1024 float4), coalesced
    const float4* A4 = (const float4*)(attn + (size_t)(b*TD + t0) * TE);
    at4[tid]       = A4[tid];
    at4[tid + 512] = A4[tid + 512];
    __syncthreads();

    float4 acc[8];
    #pragma unroll
    for (int t = 0; t < 8; ++t) acc[t] = make_float4(0.f, 0.f, 0.f, 0.f);

    const float4* eb = (const float4*)enc + (size_t)(b*TE)*128 + dh*64 + dq;
    for (int ec = 0; ec < 16; ++ec){
        const int e0 = eq*64 + ec*4;
        float4 x0 = eb[(size_t)(e0 + 0) * 128];
        float4 x1 = eb[(size_t)(e0 + 1) * 128];
        float4 x2 = eb[(size_t)(e0 + 2) * 128];
        float4 x3 = eb[(size_t)(e0 + 3) * 128];
        #pragma unroll
        for (int t = 0; t < 8; ++t){
            float4 w = at4[t*128 + (e0 >> 2)];     // wave-uniform broadcast
            acc[t].x += x0.x*w.x + x1.x*w.y + x2.x*w.z + x3.x*w.w;
            acc[t].y += x0.y*w.x + x1.y*w.y + x2.y*w.z + x3.y*w.w;
            acc[t].z += x0.z*w.x + x1.z*w.y + x2.z*w.z + x3.z*w.w;
            acc[t].w += x0.w*w.x + x1.w*w.y + x2.w*w.z + x3.w*w.w;
        }
    }

    // tree-reduce over eq = 8 -> 1
    for (int step = 4; step >= 1; step >>= 1){
        if (eq >= step && eq < 2*step){
            #pragma unroll
            for (int t = 0; t < 8; ++t)
                red4[t*256 + (eq - step)*64 + dq] = acc[t];
        }
        __syncthreads();
        if (eq < step){
            #pragma unroll
            for (int t = 0; t < 8; ++t){
                float4 r = red4[t*256 + eq*64 + dq];
                acc[t].x += r.x; acc[t].y += r.y; acc[t].z += r.z; acc[t].w += r.w;
            }
        }
        __syncthreads();
    }

    if (eq == 0){
        float4* ob = (float4*)ctx_out + (size_t)(b*TD + t0)*128 + dh*64 + dq;
        #pragma unroll
        for (int t = 0; t < 8; ++t) ob[t*128] = acc[t];
    }
}

extern "C" void kernel_launch(void* const* d_in, const int* in_sizes, int n_in,
                              void* d_out, int out_size, void* d_ws, size_t ws_size,
                              hipStream_t stream){
    const float* enc = (const float*)d_in[0];
    const float* dec = (const float*)d_in[1];
    const float* W1w = (const float*)d_in[2];
    const float* W1b = (const float*)d_in[3];
    const float* W2w = (const float*)d_in[4];
    const float* W2b = (const float*)d_in[5];
    const float* Vw  = (const float*)d_in[6];

    float* encT = (float*)d_ws;                       // [B,U,TE] f32 = 1 MB (exp domain)
    float* decp = encT + (size_t)B*U*TE;              // [B*TD,U] f32 = 0.5 MB (exp domain)

    float* outp     = (float*)d_out;                  // context [B,TD,DE]
    float* attn_out = outp + (size_t)B*TD*DE;         // attn    [B,TD,TE]

    hipLaunchKernelGGL(proj_fused_kernel, dim3(384), dim3(128), 0, stream,
                       enc, dec, W1w, W1b, W2w, W2b, encT, decp);
    hipLaunchKernelGGL(score_kernel, dim3(B*TD/4), dim3(256), 0, stream,
                       encT, decp, Vw, attn_out);
    hipLaunchKernelGGL(context_kernel, dim3(B*TD/8*2), dim3(512), 0, stream,
                       enc, attn_out, outp);
}

// Round 2
// 113.353 us; speedup vs baseline: 1.1856x; 1.0680x over previous
//
#include <hip/hip_runtime.h>

#define B  4
#define TE 512
#define TD 256
#define DE 512
#define U  128

#define RCPF(x)  __builtin_amdgcn_rcpf(x)
#define EXP2F(x) __builtin_amdgcn_exp2f(x)

// ---------------------------------------------------------------------------
// Fused projections, output in EXP DOMAIN: E = exp(2 * (x@W + b)).
// score kernel uses tanh(a+d) = 1 - 2/(Ea*Ed + 1); the constant term of the
// score is e-independent and cancels in softmax.
// blocks 0..255: enc side, output TRANSPOSED as encT[b][u][e] (LDS transpose).
// blocks 256..383: dec side, natural [t][u] layout.
// 8 rows/block, 256 threads. K-SPLIT: each wave owns one d-quarter (ds=tid>>6),
// each thread owns 4 rows (g, g+2, g+4, g+6). The 4 waves jointly stream W
// exactly ONCE per block (no cross-wave duplication); partial sums are
// reduced through LDS by wave 0.
// ---------------------------------------------------------------------------
#define ROWFMA(ar, xr) \
    ar.x += xr.x*w0.x + xr.y*w1.x + xr.z*w2.x + xr.w*w3.x; \
    ar.y += xr.x*w0.y + xr.y*w1.y + xr.z*w2.y + xr.w*w3.y; \
    ar.z += xr.x*w0.z + xr.y*w1.z + xr.z*w2.z + xr.w*w3.z; \
    ar.w += xr.x*w0.w + xr.y*w1.w + xr.z*w2.w + xr.w*w3.w;

#define ADD4(d, s) d.x += s.x; d.y += s.y; d.z += s.z; d.w += s.w;

__global__ __launch_bounds__(256) void proj_fused_kernel(
        const float* __restrict__ enc, const float* __restrict__ dec,
        const float* __restrict__ W1w, const float* __restrict__ W1b,
        const float* __restrict__ W2w, const float* __restrict__ W2b,
        float* __restrict__ encT, float* __restrict__ decp){
    __shared__ float4 Xs[8 * 128];      // 8 rows x 512 f32 = 16 KB
    __shared__ float4 Ps[3 * 4 * 64];   // partials [ds-1][row][g*32+q] = 12 KB
    float* T = (float*)Xs;              // aliased transpose buffer
    const int tid = threadIdx.x;

    const bool is_enc = blockIdx.x < 256;
    const float *X, *W, *bias; int r0;
    if (is_enc){ r0 = blockIdx.x * 8;         X = enc; W = W1w; bias = W1b; }
    else       { r0 = (blockIdx.x - 256) * 8; X = dec; W = W2w; bias = W2b; }

    // stage 8 rows of X (1024 float4), coalesced, 4 per thread
    const float4* Xg = (const float4*)(X + (size_t)r0 * 512);
    #pragma unroll
    for (int j = 0; j < 4; ++j)
        Xs[j * 256 + tid] = Xg[j * 256 + tid];
    __syncthreads();

    const int q  = tid & 31;          // u-quad: u0 = 4q
    const int g  = (tid >> 5) & 1;    // rows g, g+2, g+4, g+6
    const int ds = tid >> 6;          // d-quarter, one per wave
    const float4* W4 = (const float4*)W;   // row d = 32 float4

    float4 a0, a1, a2, a3;
    a0 = a1 = a2 = a3 = make_float4(0.f, 0.f, 0.f, 0.f);

    const int dbase = ds * 128;
    #pragma unroll 2
    for (int dd = 0; dd < 128; dd += 4){
        const int d0 = dbase + dd;
        const int xq = d0 >> 2;
        float4 x0 = Xs[(g + 0) * 128 + xq];     // LDS broadcast
        float4 x1 = Xs[(g + 2) * 128 + xq];
        float4 x2 = Xs[(g + 4) * 128 + xq];
        float4 x3 = Xs[(g + 6) * 128 + xq];
        float4 w0 = W4[(d0 + 0) * 32 + q];
        float4 w1 = W4[(d0 + 1) * 32 + q];
        float4 w2 = W4[(d0 + 2) * 32 + q];
        float4 w3 = W4[(d0 + 3) * 32 + q];
        ROWFMA(a0, x0)
        ROWFMA(a1, x1)
        ROWFMA(a2, x2)
        ROWFMA(a3, x3)
    }

    const int slot = (g << 5) | q;
    if (ds){
        Ps[((ds-1)*4 + 0)*64 + slot] = a0;
        Ps[((ds-1)*4 + 1)*64 + slot] = a1;
        Ps[((ds-1)*4 + 2)*64 + slot] = a2;
        Ps[((ds-1)*4 + 3)*64 + slot] = a3;
    }
    __syncthreads();                           // partials ready; Xs reads done

    if (ds == 0){
        #pragma unroll
        for (int p = 0; p < 3; ++p){
            float4 r;
            r = Ps[(p*4 + 0)*64 + slot]; ADD4(a0, r)
            r = Ps[(p*4 + 1)*64 + slot]; ADD4(a1, r)
            r = Ps[(p*4 + 2)*64 + slot]; ADD4(a2, r)
            r = Ps[(p*4 + 3)*64 + slot]; ADD4(a3, r)
        }
        float4 bq = ((const float4*)bias)[q];
        ADD4(a0, bq) ADD4(a1, bq) ADD4(a2, bq) ADD4(a3, bq)

        // exp-domain transform: E = exp(2*p) = exp2(p * 2*log2(e))
        const float C2 = 2.8853900817779268f;
        a0.x = EXP2F(a0.x*C2); a0.y = EXP2F(a0.y*C2); a0.z = EXP2F(a0.z*C2); a0.w = EXP2F(a0.w*C2);
        a1.x = EXP2F(a1.x*C2); a1.y = EXP2F(a1.y*C2); a1.z = EXP2F(a1.z*C2); a1.w = EXP2F(a1.w*C2);
        a2.x = EXP2F(a2.x*C2); a2.y = EXP2F(a2.y*C2); a2.z = EXP2F(a2.z*C2); a2.w = EXP2F(a2.w*C2);
        a3.x = EXP2F(a3.x*C2); a3.y = EXP2F(a3.y*C2); a3.z = EXP2F(a3.z*C2); a3.w = EXP2F(a3.w*C2);

        if (is_enc){
            // T[u][e_local], u-stride 9 (pad breaks power-of-2 banks)
            T[(4*q+0)*9 + g + 0] = a0.x; T[(4*q+1)*9 + g + 0] = a0.y;
            T[(4*q+2)*9 + g + 0] = a0.z; T[(4*q+3)*9 + g + 0] = a0.w;
            T[(4*q+0)*9 + g + 2] = a1.x; T[(4*q+1)*9 + g + 2] = a1.y;
            T[(4*q+2)*9 + g + 2] = a1.z; T[(4*q+3)*9 + g + 2] = a1.w;
            T[(4*q+0)*9 + g + 4] = a2.x; T[(4*q+1)*9 + g + 4] = a2.y;
            T[(4*q+2)*9 + g + 4] = a2.z; T[(4*q+3)*9 + g + 4] = a2.w;
            T[(4*q+0)*9 + g + 6] = a3.x; T[(4*q+1)*9 + g + 6] = a3.y;
            T[(4*q+2)*9 + g + 6] = a3.z; T[(4*q+3)*9 + g + 6] = a3.w;
        } else {
            float4* D = (float4*)decp;
            D[(size_t)(r0 + g + 0) * 32 + q] = a0;
            D[(size_t)(r0 + g + 2) * 32 + q] = a1;
            D[(size_t)(r0 + g + 4) * 32 + q] = a2;
            D[(size_t)(r0 + g + 6) * 32 + q] = a3;
        }
    }
    __syncthreads();                           // T ready (uniform barrier)

    if (is_enc && tid < 128){
        const int u  = tid;
        const int bb = r0 >> 9;        // 512 rows per batch
        const int et = r0 & 511;       // e-tile base
        float4 lo = make_float4(T[u*9+0], T[u*9+1], T[u*9+2], T[u*9+3]);
        float4 hi = make_float4(T[u*9+4], T[u*9+5], T[u*9+6], T[u*9+7]);
        float4* row = (float4*)encT + (size_t)(bb*U + u)*128 + (et >> 2);
        row[0] = lo; row[1] = hi;
    }
}

// ---------------------------------------------------------------------------
// Score + softmax, exp-factorized tanh:
//   logits[e] = sum_u (-2*V_u) * rcp(Ea[u][e]*Ed[t][u] + 1)
// block = (b, t-quad), 512 threads. Each thread handles ALL 4 t's for its
// 4 e's (no cross-wave Ea duplication: every Ea float4 read once per block),
// and u is quarter-split across waves (uh = tid>>7); partials combined in LDS
// before the softmax, which runs on the uh==0 waves.
// ---------------------------------------------------------------------------
#define TANH_ACC(s, dv) \
    s.x += wv * RCPF(fmaf(A.x, dv, 1.0f)); \
    s.y += wv * RCPF(fmaf(A.y, dv, 1.0f)); \
    s.z += wv * RCPF(fmaf(A.z, dv, 1.0f)); \
    s.w += wv * RCPF(fmaf(A.w, dv, 1.0f));

__global__ __launch_bounds__(512) void score_kernel(
        const float* __restrict__ encT, const float* __restrict__ decp,
        const float* __restrict__ Vw, float* __restrict__ attn_out){
    __shared__ float4 dp4[128];          // Ed rows t0..t0+3 (4 x 128 f32)
    __shared__ float4 vv4[32];           // -2*V (128 f32)
    __shared__ float4 Pp[3 * 4 * 128];   // partials [uh-1][t][eq] = 24 KB
    __shared__ float redm[8], reds[8];   // [t][wave-half]
    const float* dpf = (const float*)dp4;
    const float* vvf = (const float*)vv4;
    const int tid = threadIdx.x;
    const int b  = blockIdx.x >> 6;
    const int t0 = (blockIdx.x & 63) * 4;

    if (tid < 128){
        dp4[tid] = ((const float4*)decp)[(size_t)(b*TD + t0 + (tid>>5))*32 + (tid&31)];
    } else if (tid < 160){
        float4 v = ((const float4*)Vw)[tid - 128];
        vv4[tid - 128] = make_float4(-2.f*v.x, -2.f*v.y, -2.f*v.z, -2.f*v.w);
    }
    __syncthreads();

    const int uh = tid >> 7;         // u-quarter 0..3 (uniform per wave pair)
    const int eq = tid & 127;        // e-quad: e0 = 4*eq
    const int u0 = uh * 32;

    const float4* E  = (const float4*)encT + (size_t)b*U*128 + (size_t)u0*128 + eq;
    const float* dt0 = dpf + 0*128 + u0;
    const float* dt1 = dpf + 1*128 + u0;
    const float* dt2 = dpf + 2*128 + u0;
    const float* dt3 = dpf + 3*128 + u0;
    const float* vv  = vvf + u0;

    float4 s0, s1, s2, s3;
    s0 = s1 = s2 = s3 = make_float4(0.f, 0.f, 0.f, 0.f);

    #pragma unroll 4
    for (int u = 0; u < 32; ++u){
        float4 A = E[(size_t)u * 128];        // coalesced across e-lanes
        float d0 = dt0[u], d1 = dt1[u], d2 = dt2[u], d3 = dt3[u];
        float wv = vv[u];
        TANH_ACC(s0, d0)
        TANH_ACC(s1, d1)
        TANH_ACC(s2, d2)
        TANH_ACC(s3, d3)
    }

    if (uh){
        Pp[((uh-1)*4 + 0)*128 + eq] = s0;
        Pp[((uh-1)*4 + 1)*128 + eq] = s1;
        Pp[((uh-1)*4 + 2)*128 + eq] = s2;
        Pp[((uh-1)*4 + 3)*128 + eq] = s3;
    }
    __syncthreads();

    float4 p0, p1, p2, p3;
    float m0, m1, m2, m3;
    const int w = tid >> 6;              // 0/1 within the uh==0 pair
    if (uh == 0){
        #pragma unroll
        for (int p = 0; p < 3; ++p){
            float4 r;
            r = Pp[(p*4 + 0)*128 + eq]; ADD4(s0, r)
            r = Pp[(p*4 + 1)*128 + eq]; ADD4(s1, r)
            r = Pp[(p*4 + 2)*128 + eq]; ADD4(s2, r)
            r = Pp[(p*4 + 3)*128 + eq]; ADD4(s3, r)
        }
        m0 = fmaxf(fmaxf(s0.x, s0.y), fmaxf(s0.z, s0.w));
        m1 = fmaxf(fmaxf(s1.x, s1.y), fmaxf(s1.z, s1.w));
        m2 = fmaxf(fmaxf(s2.x, s2.y), fmaxf(s2.z, s2.w));
        m3 = fmaxf(fmaxf(s3.x, s3.y), fmaxf(s3.z, s3.w));
        for (int o = 32; o > 0; o >>= 1){
            m0 = fmaxf(m0, __shfl_xor(m0, o));
            m1 = fmaxf(m1, __shfl_xor(m1, o));
            m2 = fmaxf(m2, __shfl_xor(m2, o));
            m3 = fmaxf(m3, __shfl_xor(m3, o));
        }
        if ((tid & 63) == 0){
            redm[0*2 + w] = m0; redm[1*2 + w] = m1;
            redm[2*2 + w] = m2; redm[3*2 + w] = m3;
        }
    }
    __syncthreads();
    if (uh == 0){
        m0 = fmaxf(redm[0], redm[1]); m1 = fmaxf(redm[2], redm[3]);
        m2 = fmaxf(redm[4], redm[5]); m3 = fmaxf(redm[6], redm[7]);
        const float L2E = 1.4426950408889634f;
        p0.x = EXP2F((s0.x-m0)*L2E); p0.y = EXP2F((s0.y-m0)*L2E);
        p0.z = EXP2F((s0.z-m0)*L2E); p0.w = EXP2F((s0.w-m0)*L2E);
        p1.x = EXP2F((s1.x-m1)*L2E); p1.y = EXP2F((s1.y-m1)*L2E);
        p1.z = EXP2F((s1.z-m1)*L2E); p1.w = EXP2F((s1.w-m1)*L2E);
        p2.x = EXP2F((s2.x-m2)*L2E); p2.y = EXP2F((s2.y-m2)*L2E);
        p2.z = EXP2F((s2.z-m2)*L2E); p2.w = EXP2F((s2.w-m2)*L2E);
        p3.x = EXP2F((s3.x-m3)*L2E); p3.y = EXP2F((s3.y-m3)*L2E);
        p3.z = EXP2F((s3.z-m3)*L2E); p3.w = EXP2F((s3.w-m3)*L2E);
        float l0 = (p0.x+p0.y)+(p0.z+p0.w);
        float l1 = (p1.x+p1.y)+(p1.z+p1.w);
        float l2 = (p2.x+p2.y)+(p2.z+p2.w);
        float l3 = (p3.x+p3.y)+(p3.z+p3.w);
        for (int o = 32; o > 0; o >>= 1){
            l0 += __shfl_xor(l0, o); l1 += __shfl_xor(l1, o);
            l2 += __shfl_xor(l2, o); l3 += __shfl_xor(l3, o);
        }
        if ((tid & 63) == 0){
            reds[0*2 + w] = l0; reds[1*2 + w] = l1;
            reds[2*2 + w] = l2; reds[3*2 + w] = l3;
        }
    }
    __syncthreads();
    if (uh == 0){
        float i0 = RCPF(reds[0] + reds[1]);
        float i1 = RCPF(reds[2] + reds[3]);
        float i2 = RCPF(reds[4] + reds[5]);
        float i3 = RCPF(reds[6] + reds[7]);
        float4* O = (float4*)attn_out;
        O[(size_t)(b*TD + t0 + 0)*128 + eq] = make_float4(p0.x*i0, p0.y*i0, p0.z*i0, p0.w*i0);
        O[(size_t)(b*TD + t0 + 1)*128 + eq] = make_float4(p1.x*i1, p1.y*i1, p1.z*i1, p1.w*i1);
        O[(size_t)(b*TD + t0 + 2)*128 + eq] = make_float4(p2.x*i2, p2.y*i2, p2.z*i2, p2.w*i2);
        O[(size_t)(b*TD + t0 + 3)*128 + eq] = make_float4(p3.x*i3, p3.y*i3, p3.z*i3, p3.w*i3);
    }
}

// ---------------------------------------------------------------------------
// context[b,t,d] = sum_e attn[b,t,e]*enc[b,e,d].
// block = (b, t-oct, d-half), 512 threads: dq = tid&63 (d-quad within half),
// eq = tid>>6 (e-eighth, 64 e's each). LDS tree-reduce over the 8 e-groups.
// ---------------------------------------------------------------------------
__global__ __launch_bounds__(512) void context_kernel(
        const float* __restrict__ enc, const float* __restrict__ attn,
        float* __restrict__ ctx_out){
    __shared__ float4 at4[8 * 128];      // attn rows [t][e-quad], 16 KB
    __shared__ float4 red4[8 * 256];     // reduce buffer [t][4 groups][64], 32 KB
    const int tid = threadIdx.x;
    const int dh = blockIdx.x & 1;             // d-half
    const int b  = (blockIdx.x >> 1) & 3;      // ~XCD-resident batch
    const int t0 = (blockIdx.x >> 3) * 8;      // t-oct
    const int dq = tid & 63;
    const int eq = tid >> 6;

    // stage 8 attn rows (1024 float4), coalesced
    const float4* A4 = (const float4*)(attn + (size_t)(b*TD + t0) * TE);
    at4[tid]       = A4[tid];
    at4[tid + 512] = A4[tid + 512];
    __syncthreads();

    float4 acc[8];
    #pragma unroll
    for (int t = 0; t < 8; ++t) acc[t] = make_float4(0.f, 0.f, 0.f, 0.f);

    const float4* eb = (const float4*)enc + (size_t)(b*TE)*128 + dh*64 + dq;
    for (int ec = 0; ec < 16; ++ec){
        const int e0 = eq*64 + ec*4;
        float4 x0 = eb[(size_t)(e0 + 0) * 128];
        float4 x1 = eb[(size_t)(e0 + 1) * 128];
        float4 x2 = eb[(size_t)(e0 + 2) * 128];
        float4 x3 = eb[(size_t)(e0 + 3) * 128];
        #pragma unroll
        for (int t = 0; t < 8; ++t){
            float4 w = at4[t*128 + (e0 >> 2)];     // wave-uniform broadcast
            acc[t].x += x0.x*w.x + x1.x*w.y + x2.x*w.z + x3.x*w.w;
            acc[t].y += x0.y*w.x + x1.y*w.y + x2.y*w.z + x3.y*w.w;
            acc[t].z += x0.z*w.x + x1.z*w.y + x2.z*w.z + x3.z*w.w;
            acc[t].w += x0.w*w.x + x1.w*w.y + x2.w*w.z + x3.w*w.w;
        }
    }

    // tree-reduce over eq = 8 -> 1
    for (int step = 4; step >= 1; step >>= 1){
        if (eq >= step && eq < 2*step){
            #pragma unroll
            for (int t = 0; t < 8; ++t)
                red4[t*256 + (eq - step)*64 + dq] = acc[t];
        }
        __syncthreads();
        if (eq < step){
            #pragma unroll
            for (int t = 0; t < 8; ++t){
                float4 r = red4[t*256 + eq*64 + dq];
                acc[t].x += r.x; acc[t].y += r.y; acc[t].z += r.z; acc[t].w += r.w;
            }
        }
        __syncthreads();
    }

    if (eq == 0){
        float4* ob = (float4*)ctx_out + (size_t)(b*TD + t0)*128 + dh*64 + dq;
        #pragma unroll
        for (int t = 0; t < 8; ++t) ob[t*128] = acc[t];
    }
}

extern "C" void kernel_launch(void* const* d_in, const int* in_sizes, int n_in,
                              void* d_out, int out_size, void* d_ws, size_t ws_size,
                              hipStream_t stream){
    const float* enc = (const float*)d_in[0];
    const float* dec = (const float*)d_in[1];
    const float* W1w = (const float*)d_in[2];
    const float* W1b = (const float*)d_in[3];
    const float* W2w = (const float*)d_in[4];
    const float* W2b = (const float*)d_in[5];
    const float* Vw  = (const float*)d_in[6];

    float* encT = (float*)d_ws;                       // [B,U,TE] f32 = 1 MB (exp domain)
    float* decp = encT + (size_t)B*U*TE;              // [B*TD,U] f32 = 0.5 MB (exp domain)

    float* outp     = (float*)d_out;                  // context [B,TD,DE]
    float* attn_out = outp + (size_t)B*TD*DE;         // attn    [B,TD,TE]

    hipLaunchKernelGGL(proj_fused_kernel, dim3(384), dim3(256), 0, stream,
                       enc, dec, W1w, W1b, W2w, W2b, encT, decp);
    hipLaunchKernelGGL(score_kernel, dim3(B*TD/4), dim3(512), 0, stream,
                       encT, decp, Vw, attn_out);
    hipLaunchKernelGGL(context_kernel, dim3(B*TD/8*2), dim3(512), 0, stream,
                       enc, attn_out, outp);
}